// Round 7
// baseline (167.159 us; speedup 1.0000x reference)
//
#include <hip/hip_runtime.h>

// DiffVolumeV2: out[b][c][d][h][x] = left[b][c][h][x] - right[b][c][h][clip(4x-d+1, 0, Wr-1)]
// B=4, C=32, H=80, Wl=160, Wr=640, D=48.
// 314.6 MB out + 32.8 MB in. Fill kernel sustains ~6.9 TB/s pure-write on this chip.
//
// R1 72.5 | R2 117 (lockstep) | R3 69.5 | R4 71.9 | R6 66.4 (nt stores on R3).
// All LDS-staged variants pin at ~5.0-5.2 TB/s: not issue-, VALU-, or LDS-bound.
// R7 isolates the last structural variable: CHIP-WIDE WRITE ORDER. Dense grid-stride
// sweep of the output in flat memory order (fill-kernel shape), no LDS, no barrier:
//  - grid-stride = exactly 8 bc-volumes (4800 blocks x 256 thr, 16 iters) =>
//    (d,h,x4) and the 4 clipped gather offsets are PER-THREAD CONSTANTS;
//    per iter only 3 base pointers bump.
//  - right/left read through L2 (8-bc working set = 2 MB, reused 48x) -- NOT nt.
//  - output stores nontemporal, 9.8 MB dense moving front per iter step.

typedef float fx4 __attribute__((ext_vector_type(4)));

constexpr int Bc  = 4;
constexpr int Cc  = 32;
constexpr int Hc  = 80;
constexpr int WLc = 160;
constexpr int WRc = 640;

constexpr int Dc      = 48;
constexpr int PLANE4  = Hc * WLc / 4;          // 3200 out-float4 per (bc,d) plane
constexpr int BCVOL4  = Dc * PLANE4;           // 153600 out-float4 per bc
constexpr int TOTAL4  = Bc * Cc * BCVOL4;      // 19,660,800
constexpr int TPB     = 256;
constexpr int STRIDE4 = 8 * BCVOL4;            // 1,228,800 = 8 bc per front
constexpr int NBLK    = STRIDE4 / TPB;         // 4800 blocks
constexpr int NITER   = TOTAL4 / STRIDE4;      // 16

__global__ __launch_bounds__(TPB) void diffvol48_dense(
    const float* __restrict__ left, const float* __restrict__ right,
    float* __restrict__ out)
{
    const int gid = blockIdx.x * TPB + threadIdx.x;     // [0, STRIDE4)

    // Decompose once: gid = ((bc0*48 + d)*80 + h)*40 + x4
    const int x4  = gid % 40;
    const int r1  = gid / 40;
    const int h   = r1 % Hc;
    const int r2  = r1 / Hc;
    const int d   = r2 % Dc;
    const int bc0 = r2 / Dc;                            // 0..7

    // Per-thread constant gather offsets within the right row.
    int c0 = 16 * x4 + 1 - d;                           // + 4j, j=0..3; max 637 < 639
    int rofs[4];
    #pragma unroll
    for (int j = 0; j < 4; ++j) { int c = c0 + 4 * j; rofs[j] = c < 0 ? 0 : c; }

    const float* lptr = left  + (size_t)bc0 * (Hc * WLc) + h * WLc + x4 * 4;
    const float* rptr = right + (size_t)bc0 * (Hc * WRc) + h * WRc;
    float*       optr = out   + (size_t)gid * 4;

    #pragma unroll 4
    for (int k = 0; k < NITER; ++k) {
        const fx4 lv = *(const fx4*)lptr;               // L2-hot (reused by 48 d's this iter)
        fx4 v;
        #pragma unroll
        for (int j = 0; j < 4; ++j)
            v[j] = lv[j] - rptr[rofs[j]];               // coalesced 16B-stride gather, L2-hot
        __builtin_nontemporal_store(v, (fx4*)optr);     // dense moving front

        lptr += 8 * (Hc * WLc);
        rptr += 8 * (Hc * WRc);
        optr += (size_t)STRIDE4 * 4;
    }
}

// Generic fallback (any D) — proven R6 kernel.
constexpr int GROUPS = WLc / 4;
constexpr int RPAD = WRc + WRc / 32;
__global__ __launch_bounds__(TPB) void diffvol_generic(
    const float* __restrict__ left, const float* __restrict__ right,
    float* __restrict__ out, int D)
{
    __shared__ __align__(16) float lrow[WLc];
    __shared__ float rrow[RPAD];

    const int blk = blockIdx.x;
    const int h   = blk % Hc;
    const int bc  = blk / Hc;
    const float* lp = left  + ((size_t)bc * Hc + h) * WLc;
    const float* rp = right + ((size_t)bc * Hc + h) * WRc;
    const int tid = threadIdx.x;

    if (tid < WLc) lrow[tid] = lp[tid];
    for (int i = tid; i < WRc; i += TPB) rrow[i + (i >> 5)] = rp[i];
    __syncthreads();

    float* ob = out + ((size_t)bc * D * Hc + h) * WLc;
    const int total = D * GROUPS;
    for (int t = tid; t < total; t += TPB) {
        const int d  = t / GROUPS;
        const int g  = t - d * GROUPS;
        const int x0 = g * 4;
        const fx4 lv = *(const fx4*)(lrow + x0);
        fx4 v;
        #pragma unroll
        for (int j = 0; j < 4; ++j) {
            int r = 4 * (x0 + j) - d + 1;
            r = r < 0 ? 0 : r;
            v[j] = lv[j] - rrow[r + (r >> 5)];
        }
        __builtin_nontemporal_store(v, (fx4*)(ob + (size_t)d * (Hc * WLc) + x0));
    }
}

extern "C" void kernel_launch(void* const* d_in, const int* in_sizes, int n_in,
                              void* d_out, int out_size, void* d_ws, size_t ws_size,
                              hipStream_t stream) {
    const float* left  = (const float*)d_in[0];
    const float* right = (const float*)d_in[1];
    float* out = (float*)d_out;

    const int D = out_size / (Bc * Cc * Hc * WLc);

    if (D == 48) {
        diffvol48_dense<<<dim3(NBLK), TPB, 0, stream>>>(left, right, out);
    } else {
        dim3 grid(Bc * Cc * Hc);
        diffvol_generic<<<grid, TPB, 0, stream>>>(left, right, out, D);
    }
}

// Round 8
// 68.459 us; speedup vs baseline: 2.4417x; 2.4417x over previous
//
#include <hip/hip_runtime.h>

// DiffVolumeV2: out[b][c][d][h][x] = left[b][c][h][x] - right[b][c][h][clip(4x-d+1, 0, Wr-1)]
// B=4, C=32, H=80, Wl=160, Wr=640, D=48.
// 314.6 MB out + 32.8 MB in. Fill kernel: ~6.9 TB/s pure write. Ideal mixed ~51us.
//
// R1 72.5 | R2 117 | R3 69.5 | R4 71.9 | R6 66.4 (R3+nt) | R7 167 (dense sweep:
// FETCH ballooned 33->269MB, k-phase drift killed L2 reuse -- reverted).
// R8 = R6 + bijective XCD-chunk swizzle (10240%8==0): each XCD owns 1280
// CONSECUTIVE (bc,h) blocks, so its ~256 concurrently-resident blocks write
// adjacent 640B runs (dense d-planes over ~3 bc volumes) instead of stride-8-h
// scattered runs => DRAM row-hit rate on the write stream. Single variable vs R6.

typedef float fx4 __attribute__((ext_vector_type(4)));

constexpr int Bc  = 4;
constexpr int Cc  = 32;
constexpr int Hc  = 80;
constexpr int WLc = 160;
constexpr int WRc = 640;
constexpr int TPB = 256;
constexpr int GROUPS = WLc / 4;          // 40 float4 groups per row
constexpr int RPAD = WRc + WRc / 32;     // 660: addr = i + (i>>5) kills stride-16 conflicts
constexpr int NXCD = 8;
constexpr int NBLK = Bc * Cc * Hc;       // 10240, divisible by 8

__global__ __launch_bounds__(TPB) void diffvol48(
    const float* __restrict__ left, const float* __restrict__ right,
    float* __restrict__ out)
{
    constexpr int D = 48;
    __shared__ __align__(16) float lrow[WLc];
    __shared__ float rrow[RPAD];

    // XCD-chunk swizzle: hardware assigns blockIdx round-robin over 8 XCDs;
    // remap so XCD k processes consecutive blk range [k*1280, (k+1)*1280).
    const int wg  = blockIdx.x;
    const int blk = (wg % NXCD) * (NBLK / NXCD) + wg / NXCD;

    const int h   = blk % Hc;
    const int bc  = blk / Hc;
    const float* lp = left  + ((size_t)bc * Hc + h) * WLc;
    const float* rp = right + ((size_t)bc * Hc + h) * WRc;
    const int tid = threadIdx.x;

    if (tid < GROUPS) {
        fx4 v = __builtin_nontemporal_load((const fx4*)(lp + tid * 4));
        *(fx4*)(lrow + tid * 4) = v;
    }
    if (tid < WRc / 4) {
        fx4 v = __builtin_nontemporal_load((const fx4*)(rp + tid * 4));
        #pragma unroll
        for (int k = 0; k < 4; ++k) { int c = tid * 4 + k; rrow[c + (c >> 5)] = v[k]; }
    }
    __syncthreads();

    int d = tid / GROUPS;                // 0..6 (one div, outside loop)
    int g = tid - d * GROUPS;            // 0..39
    int e = 16 * g - d;                  // gather base; c_j = e + 1 + 4j
    float* op = out + (size_t)bc * (D * Hc * WLc) + h * WLc
                    + (size_t)d * (Hc * WLc) + g * 4;

    // t += 256  <=>  g += 16 mod 40; no-wrap: d+=6, wrap: d+=7.
    #define SLOT_BODY                                                     \
    {                                                                     \
        const fx4 lv = *(const fx4*)(lrow + g * 4);                       \
        fx4 v;                                                            \
        _Pragma("unroll")                                                 \
        for (int j = 0; j < 4; ++j) {                                     \
            int c = e + 1 + 4 * j;                                        \
            c = c < 0 ? 0 : c;                                            \
            v[j] = lv[j] - rrow[c + (c >> 5)];                            \
        }                                                                 \
        __builtin_nontemporal_store(v, (fx4*)op);                         \
    }
    #define SLOT_ADVANCE                                                  \
    {                                                                     \
        int gn = g + 16;                                                  \
        bool wrap = gn >= GROUPS;                                         \
        g = wrap ? gn - GROUPS : gn;                                      \
        e += wrap ? -391 : 250;                                           \
        op += wrap ? (7 * Hc * WLc - 96) : (6 * Hc * WLc + 64);           \
    }

    #pragma unroll
    for (int it = 0; it < 7; ++it) { SLOT_BODY; SLOT_ADVANCE; }
    if (tid < (D * GROUPS - 7 * TPB)) {  // tid < 128: waves 0,1 — uniform per wave
        SLOT_BODY;
    }
    #undef SLOT_BODY
    #undef SLOT_ADVANCE
}

// Generic fallback (any D).
__global__ __launch_bounds__(TPB) void diffvol_generic(
    const float* __restrict__ left, const float* __restrict__ right,
    float* __restrict__ out, int D)
{
    __shared__ __align__(16) float lrow[WLc];
    __shared__ float rrow[RPAD];

    const int blk = blockIdx.x;
    const int h   = blk % Hc;
    const int bc  = blk / Hc;
    const float* lp = left  + ((size_t)bc * Hc + h) * WLc;
    const float* rp = right + ((size_t)bc * Hc + h) * WRc;
    const int tid = threadIdx.x;

    if (tid < WLc) lrow[tid] = lp[tid];
    for (int i = tid; i < WRc; i += TPB) rrow[i + (i >> 5)] = rp[i];
    __syncthreads();

    float* ob = out + ((size_t)bc * D * Hc + h) * WLc;
    const int total = D * (WLc / 4);
    for (int t = tid; t < total; t += TPB) {
        const int d  = t / (WLc / 4);
        const int g  = t - d * (WLc / 4);
        const int x0 = g * 4;
        const fx4 lv = *(const fx4*)(lrow + x0);
        fx4 v;
        #pragma unroll
        for (int j = 0; j < 4; ++j) {
            int r = 4 * (x0 + j) - d + 1;
            r = r < 0 ? 0 : r;
            v[j] = lv[j] - rrow[r + (r >> 5)];
        }
        __builtin_nontemporal_store(v, (fx4*)(ob + (size_t)d * (Hc * WLc) + x0));
    }
}

extern "C" void kernel_launch(void* const* d_in, const int* in_sizes, int n_in,
                              void* d_out, int out_size, void* d_ws, size_t ws_size,
                              hipStream_t stream) {
    const float* left  = (const float*)d_in[0];
    const float* right = (const float*)d_in[1];
    float* out = (float*)d_out;

    const int D = out_size / (Bc * Cc * Hc * WLc);

    if (D == 48) {
        diffvol48<<<dim3(NBLK), TPB, 0, stream>>>(left, right, out);
    } else {
        dim3 grid(Bc * Cc * Hc);
        diffvol_generic<<<grid, TPB, 0, stream>>>(left, right, out, D);
    }
}